// Round 13
// baseline (38.559 us; speedup 1.0000x reference)
//
#include <hip/hip_runtime.h>

// ZNCC 5x5, zero-padded, count_include_pad means.
// x,y: (4,3,512,512) f32 -> out: (4,1,512,512) f32
// Round 13: R12 (packed-f32 interleaved (x,y) LDS, batched window regs,
// pipelined dbuf staging) + two changes:
//  (a) Newton-rsqrt: bit-hack seed + 1 NR (6 full-rate VALU) replaces
//      v_rsq_f32 (trans pipe, 8-16 cyc) -> moves ~1/3 of kernel cycles
//      from the trans pipe to cheap VALU. err <= 0.18% rel, well under thr.
//  (b) channel loop re-rolled (#pragma unroll 1, runtime buffer select):
//      code size ~34KB -> ~12KB (I$ pressure), zero math change.

constexpr int W  = 512, H = 512, C = 3, NB = 4;
constexpr int PLANE = H * W;
constexpr int TW = 64, TH = 32, HALO = 2;
constexpr int LW = TW + 2 * HALO;   // 68 pairs per row
constexpr int LH = TH + 2 * HALO;   // 36
constexpr int LSZ  = LW * LH;       // 2448 pairs
constexpr int LPAD = 2560;          // 10 chunks * 256 threads
constexpr int NPF  = 10;

typedef float f2 __attribute__((ext_vector_type(2)));

__device__ __forceinline__ float fast_rsqrt(float d) {
    // Quake seed + 1 Newton step: rel err <= 0.18%, all full-rate VALU.
    float y = __uint_as_float(0x5f375a86u - (__float_as_uint(d) >> 1));
    return y * __builtin_fmaf(-0.5f * d, y * y, 1.5f);
}

__device__ __forceinline__ void prefetch_plane(const float* __restrict__ xb,
                                               const float* __restrict__ yb,
                                               const int* goff, const float* fm,
                                               float* px, float* py) {
    #pragma unroll
    for (int k = 0; k < NPF; ++k) {
        px[k] = xb[goff[k]] * fm[k];
        py[k] = yb[goff[k]] * fm[k];
    }
}

__device__ __forceinline__ void write_tile(f2* __restrict__ dst,
                                           const float* px, const float* py,
                                           int tid) {
    #pragma unroll
    for (int k = 0; k < NPF; ++k) {
        f2 v; v.x = px[k]; v.y = py[k];
        dst[tid + 256 * k] = v;                 // ds_write_b64
    }
}

// Full 8-row x 6-pair window batched into registers; rolling colsum in regs.
__device__ __forceinline__ void compute_channel(const f2* __restrict__ tile,
                                                int ry, int cx,
                                                float* ch0, float* ch1) {
    const float EPS = 1e-4f;
    const f2 EPS2 = {1e-4f, 1e-4f};

    // ---- one burst: 24 independent ds_read_b128 ----
    f2 w[8][6];
    #pragma unroll
    for (int k = 0; k < 8; ++k) {
        const int base = (4 * ry + k) * LW + cx;
        const float4 u0 = *reinterpret_cast<const float4*>(&tile[base]);
        const float4 u1 = *reinterpret_cast<const float4*>(&tile[base + 2]);
        const float4 u2 = *reinterpret_cast<const float4*>(&tile[base + 4]);
        w[k][0] = f2{u0.x, u0.y}; w[k][1] = f2{u0.z, u0.w};
        w[k][2] = f2{u1.x, u1.y}; w[k][3] = f2{u1.z, u1.w};
        w[k][4] = f2{u2.x, u2.y}; w[k][5] = f2{u2.z, u2.w};
    }

    // ---- init column sums from rows 0..3 ----
    f2 cs[6];
    #pragma unroll
    for (int j = 0; j < 6; ++j)
        cs[j] = (w[0][j] + w[1][j]) + (w[2][j] + w[3][j]);

    #pragma unroll
    for (int o = 0; o < 4; ++o) {
        #pragma unroll
        for (int j = 0; j < 6; ++j) cs[j] += w[o + 4][j];

        // means for px0 (cols 0..4) and px1 (cols 1..5), both images packed
        const f2 m4 = (cs[1] + cs[2]) + (cs[3] + cs[4]);
        const f2 M0 = (m4 + cs[0]) * (1.f / 25.f);   // (mx0, my0)
        const f2 M1 = (m4 + cs[5]) * (1.f / 25.f);   // (mx1, my1)

        float a0 = 0.f, a1 = 0.f;
        #pragma unroll
        for (int k = 0; k < 5; ++k) {
            #pragma unroll
            for (int j = 0; j < 5; ++j) {
                {
                    const f2 d = w[o + k][j] - M0;                      // pk_add
                    const float t = d.x * d.y;
                    const float num = fabsf(t) + EPS;
                    const f2 q = __builtin_elementwise_fma(d, d, EPS2); // pk_fma
                    const float den = q.x * q.y;
                    a0 += num * fast_rsqrt(den);
                }
                {
                    const f2 d = w[o + k][j + 1] - M1;
                    const float t = d.x * d.y;
                    const float num = fabsf(t) + EPS;
                    const f2 q = __builtin_elementwise_fma(d, d, EPS2);
                    const float den = q.x * q.y;
                    a1 += num * fast_rsqrt(den);
                }
            }
        }
        ch0[o] += fminf(fmaxf(a0 * (1.f / 25.f), 0.f), 1.f);
        ch1[o] += fminf(fmaxf(a1 * (1.f / 25.f), 0.f), 1.f);

        #pragma unroll
        for (int j = 0; j < 6; ++j) cs[j] -= w[o][j];
    }
}

__global__ __launch_bounds__(256, 2)
void zncc_kernel(const float* __restrict__ x,
                 const float* __restrict__ y,
                 float* __restrict__ out) {
    __shared__ f2 sb0[LPAD];            // interleaved (x,y) tiles, dbuf
    __shared__ f2 sb1[LPAD];            // 40960 B total

    const int tid = threadIdx.x;
    const int tx  = tid & 31;           // 32 col-pairs -> 64 cols
    const int ry  = tid >> 5;           // 0..7 -> rows 4*ry..4*ry+3
    const int cx  = 2 * tx;
    const int w0  = blockIdx.x * TW;
    const int h0  = blockIdx.y * TH;
    const int b   = blockIdx.z;

    // staging address math, once (reused for all 3 channels)
    int   goff[NPF];
    float fm[NPF];
    #pragma unroll
    for (int k = 0; k < NPF; ++k) {
        const int i  = tid + 256 * k;
        const int l  = i / LW;
        const int m  = i - l * LW;
        const int gr = h0 + l - HALO;
        const int gc = w0 + m - HALO;
        const bool ok = (i < LSZ) && ((unsigned)gr < (unsigned)H) &&
                        ((unsigned)gc < (unsigned)W);
        goff[k] = ok ? gr * W + gc : 0;
        fm[k]   = ok ? 1.f : 0.f;
    }

    const float* xb0 = x + (size_t)(b * C) * PLANE;
    const float* yb0 = y + (size_t)(b * C) * PLANE;

    float ch0[4] = {0.f, 0.f, 0.f, 0.f};
    float ch1[4] = {0.f, 0.f, 0.f, 0.f};
    float px[NPF], py[NPF];

    // stage channel 0 -> buf0
    prefetch_plane(xb0, yb0, goff, fm, px, py);
    write_tile(&sb0[0], px, py, tid);
    __syncthreads();

    // re-rolled channel loop (code size ~1/3 of unrolled; uniform branches)
    int cur = 0;
    #pragma unroll 1
    for (int c = 0; c < C; ++c) {
        if (c + 1 < C)
            prefetch_plane(xb0 + (c + 1) * PLANE, yb0 + (c + 1) * PLANE,
                           goff, fm, px, py);

        f2* bcur = cur ? &sb1[0] : &sb0[0];
        compute_channel(bcur, ry, cx, ch0, ch1);

        if (c + 1 < C) {
            f2* bnext = cur ? &sb0[0] : &sb1[0];
            write_tile(bnext, px, py, tid);
            __syncthreads();
        }
        cur ^= 1;
    }

    // write 2x4 output strip
    #pragma unroll
    for (int o = 0; o < 4; ++o) {
        float2 v;
        v.x = ch0[o] * (1.f / 3.f);
        v.y = ch1[o] * (1.f / 3.f);
        *reinterpret_cast<float2*>(
            &out[((size_t)b * H + h0 + 4 * ry + o) * W + w0 + cx]) = v;
    }
}

extern "C" void kernel_launch(void* const* d_in, const int* in_sizes, int n_in,
                              void* d_out, int out_size, void* d_ws, size_t ws_size,
                              hipStream_t stream) {
    const float* x = (const float*)d_in[0];
    const float* y = (const float*)d_in[1];
    float* out = (float*)d_out;
    dim3 grid(W / TW, H / TH, NB);   // 8, 16, 4 = 512 blocks (2 per CU)
    zncc_kernel<<<grid, dim3(256), 0, stream>>>(x, y, out);
}

// Round 14
// 28.188 us; speedup vs baseline: 1.3679x; 1.3679x over previous
//
#include <hip/hip_runtime.h>

// ZNCC 5x5, zero-padded, count_include_pad means.
// x,y: (4,3,512,512) f32 -> out: (4,1,512,512) f32
// Round 14: exact R12 compute (packed-f32 interleaved (x,y) LDS, batched
// 8x6-pair window regs, v_rsq restored — R13 proved NR-rsqrt and the trans
// pipe were NOT the limiter; VALU issue count is) + ONE change: float2
// vectorized staging. Tile rows start at even global columns, so every
// float2 chunk is fully in- or out-of-bounds (never straddles) -> staging
// drops from 20 scalar loads + 10 ds_write_b64 to 10 float2 loads +
// 5 ds_write_b128 per thread per channel.

constexpr int W  = 512, H = 512, C = 3, NB = 4;
constexpr int PLANE = H * W;
constexpr int TW = 64, TH = 32, HALO = 2;
constexpr int LW = TW + 2 * HALO;   // 68 pairs per row
constexpr int LH = TH + 2 * HALO;   // 36
constexpr int LSZ  = LW * LH;       // 2448 pairs
constexpr int NCH  = LSZ / 2;       // 1224 float2-chunks
constexpr int LPAD = 2560;          // 1280 chunks * 2 (pad absorbs tail)
constexpr int NPF  = 5;             // chunks per thread per array

typedef float f2 __attribute__((ext_vector_type(2)));

__device__ __forceinline__ void prefetch_plane(const float* __restrict__ xb,
                                               const float* __restrict__ yb,
                                               const int* goff, const float* fm,
                                               float2* px, float2* py) {
    #pragma unroll
    for (int k = 0; k < NPF; ++k) {
        const float2 a = *reinterpret_cast<const float2*>(xb + goff[k]);
        const float2 b = *reinterpret_cast<const float2*>(yb + goff[k]);
        px[k] = make_float2(a.x * fm[k], a.y * fm[k]);
        py[k] = make_float2(b.x * fm[k], b.y * fm[k]);
    }
}

__device__ __forceinline__ void write_tile(f2* __restrict__ dst,
                                           const float2* px, const float2* py,
                                           int tid) {
    #pragma unroll
    for (int k = 0; k < NPF; ++k) {
        const int j = tid + 256 * k;                  // chunk id
        const float4 v = make_float4(px[k].x, py[k].x, px[k].y, py[k].y);
        *reinterpret_cast<float4*>(&dst[2 * j]) = v;  // ds_write_b128
    }
}

// Full 8-row x 6-pair window batched into registers; rolling colsum in regs.
__device__ __forceinline__ void compute_channel(const f2* __restrict__ tile,
                                                int ry, int cx,
                                                float* ch0, float* ch1) {
    const float EPS = 1e-4f;
    const f2 EPS2 = {1e-4f, 1e-4f};

    // ---- one burst: 24 independent ds_read_b128 ----
    f2 w[8][6];
    #pragma unroll
    for (int k = 0; k < 8; ++k) {
        const int base = (4 * ry + k) * LW + cx;
        const float4 u0 = *reinterpret_cast<const float4*>(&tile[base]);
        const float4 u1 = *reinterpret_cast<const float4*>(&tile[base + 2]);
        const float4 u2 = *reinterpret_cast<const float4*>(&tile[base + 4]);
        w[k][0] = f2{u0.x, u0.y}; w[k][1] = f2{u0.z, u0.w};
        w[k][2] = f2{u1.x, u1.y}; w[k][3] = f2{u1.z, u1.w};
        w[k][4] = f2{u2.x, u2.y}; w[k][5] = f2{u2.z, u2.w};
    }

    // ---- init column sums from rows 0..3 ----
    f2 cs[6];
    #pragma unroll
    for (int j = 0; j < 6; ++j)
        cs[j] = (w[0][j] + w[1][j]) + (w[2][j] + w[3][j]);

    #pragma unroll
    for (int o = 0; o < 4; ++o) {
        #pragma unroll
        for (int j = 0; j < 6; ++j) cs[j] += w[o + 4][j];

        // means for px0 (cols 0..4) and px1 (cols 1..5), both images packed
        const f2 m4 = (cs[1] + cs[2]) + (cs[3] + cs[4]);
        const f2 M0 = (m4 + cs[0]) * (1.f / 25.f);   // (mx0, my0)
        const f2 M1 = (m4 + cs[5]) * (1.f / 25.f);   // (mx1, my1)

        float a0 = 0.f, a1 = 0.f;
        #pragma unroll
        for (int k = 0; k < 5; ++k) {
            #pragma unroll
            for (int j = 0; j < 5; ++j) {
                {
                    const f2 d = w[o + k][j] - M0;                      // pk_add
                    const float t = d.x * d.y;
                    const float num = fabsf(t) + EPS;
                    const f2 q = __builtin_elementwise_fma(d, d, EPS2); // pk_fma
                    const float den = q.x * q.y;
                    a0 += num * __builtin_amdgcn_rsqf(den);
                }
                {
                    const f2 d = w[o + k][j + 1] - M1;
                    const float t = d.x * d.y;
                    const float num = fabsf(t) + EPS;
                    const f2 q = __builtin_elementwise_fma(d, d, EPS2);
                    const float den = q.x * q.y;
                    a1 += num * __builtin_amdgcn_rsqf(den);
                }
            }
        }
        ch0[o] += fminf(fmaxf(a0 * (1.f / 25.f), 0.f), 1.f);
        ch1[o] += fminf(fmaxf(a1 * (1.f / 25.f), 0.f), 1.f);

        #pragma unroll
        for (int j = 0; j < 6; ++j) cs[j] -= w[o][j];
    }
}

__global__ __launch_bounds__(256, 2)
void zncc_kernel(const float* __restrict__ x,
                 const float* __restrict__ y,
                 float* __restrict__ out) {
    __shared__ f2 sb[2][LPAD];          // interleaved (x,y) tiles, 40960 B

    const int tid = threadIdx.x;
    const int tx  = tid & 31;           // 32 col-pairs -> 64 cols
    const int ry  = tid >> 5;           // 0..7 -> rows 4*ry..4*ry+3
    const int cx  = 2 * tx;
    const int w0  = blockIdx.x * TW;
    const int h0  = blockIdx.y * TH;
    const int b   = blockIdx.z;

    // staging address math, once (reused for all 3 channels), chunk-based:
    // chunk j covers tile elements (2j, 2j+1): row l=j/34, cols m=2(j%34).
    // gc = w0+m-2 is always even -> a chunk never straddles the image edge.
    int   goff[NPF];
    float fm[NPF];
    #pragma unroll
    for (int k = 0; k < NPF; ++k) {
        const int j  = tid + 256 * k;
        const int l  = j / 34;
        const int m  = 2 * (j - l * 34);
        const int gr = h0 + l - HALO;
        const int gc = w0 + m - HALO;
        const bool ok = (j < NCH) && ((unsigned)gr < (unsigned)H) &&
                        ((unsigned)gc < (unsigned)W);
        goff[k] = ok ? gr * W + gc : 0;
        fm[k]   = ok ? 1.f : 0.f;
    }

    const float* xb0 = x + (size_t)(b * C) * PLANE;
    const float* yb0 = y + (size_t)(b * C) * PLANE;

    float ch0[4] = {0.f, 0.f, 0.f, 0.f};
    float ch1[4] = {0.f, 0.f, 0.f, 0.f};
    float2 px[NPF], py[NPF];

    // stage channel 0 -> buf0
    prefetch_plane(xb0, yb0, goff, fm, px, py);
    write_tile(&sb[0][0], px, py, tid);
    __syncthreads();

    // channel 0: prefetch ch1, compute from buf0, write buf1
    prefetch_plane(xb0 + PLANE, yb0 + PLANE, goff, fm, px, py);
    compute_channel(&sb[0][0], ry, cx, ch0, ch1);
    write_tile(&sb[1][0], px, py, tid);
    __syncthreads();

    // channel 1: prefetch ch2, compute from buf1, write buf0
    prefetch_plane(xb0 + 2 * PLANE, yb0 + 2 * PLANE, goff, fm, px, py);
    compute_channel(&sb[1][0], ry, cx, ch0, ch1);
    write_tile(&sb[0][0], px, py, tid);
    __syncthreads();

    // channel 2: compute from buf0
    compute_channel(&sb[0][0], ry, cx, ch0, ch1);

    // write 2x4 output strip
    #pragma unroll
    for (int o = 0; o < 4; ++o) {
        float2 v;
        v.x = ch0[o] * (1.f / 3.f);
        v.y = ch1[o] * (1.f / 3.f);
        *reinterpret_cast<float2*>(
            &out[((size_t)b * H + h0 + 4 * ry + o) * W + w0 + cx]) = v;
    }
}

extern "C" void kernel_launch(void* const* d_in, const int* in_sizes, int n_in,
                              void* d_out, int out_size, void* d_ws, size_t ws_size,
                              hipStream_t stream) {
    const float* x = (const float*)d_in[0];
    const float* y = (const float*)d_in[1];
    float* out = (float*)d_out;
    dim3 grid(W / TW, H / TH, NB);   // 8, 16, 4 = 512 blocks (2 per CU)
    zncc_kernel<<<grid, dim3(256), 0, stream>>>(x, y, out);
}

// Round 15
// 27.793 us; speedup vs baseline: 1.3874x; 1.0142x over previous
//
#include <hip/hip_runtime.h>

// ZNCC 5x5, zero-padded, count_include_pad means.
// x,y: (4,3,512,512) f32 -> out: (4,1,512,512) f32
// Round 15: R14 compute/staging verbatim, reshaped to 4-px strips
// (2col x 2row) on 64x16 tiles -> grid 1024 = 4 blocks/CU = 4 waves/SIMD
// (2x R14's). Tests whether the ~45% residual SIMD idle is burst-stall
// coverage (fixable by TLP on THIS structure) vs issue/datapath floor.
// R10's null was on the old rolling-chain structure; R12+ stalls are
// burst-shaped (window-burst lgkmcnt, prefetch vmcnt, 3 barriers).

constexpr int W  = 512, H = 512, C = 3, NB = 4;
constexpr int PLANE = H * W;
constexpr int TW = 64, TH = 16, HALO = 2;
constexpr int LW = TW + 2 * HALO;   // 68 pairs per row
constexpr int LH = TH + 2 * HALO;   // 20
constexpr int LSZ  = LW * LH;       // 1360 pairs
constexpr int NCH  = LSZ / 2;       // 680 float2-chunks
constexpr int LPAD = 1536;          // 768 chunks * 2 (pad absorbs tail)
constexpr int NPF  = 3;             // chunks per thread per array

typedef float f2 __attribute__((ext_vector_type(2)));

__device__ __forceinline__ void prefetch_plane(const float* __restrict__ xb,
                                               const float* __restrict__ yb,
                                               const int* goff, const float* fm,
                                               float2* px, float2* py) {
    #pragma unroll
    for (int k = 0; k < NPF; ++k) {
        const float2 a = *reinterpret_cast<const float2*>(xb + goff[k]);
        const float2 b = *reinterpret_cast<const float2*>(yb + goff[k]);
        px[k] = make_float2(a.x * fm[k], a.y * fm[k]);
        py[k] = make_float2(b.x * fm[k], b.y * fm[k]);
    }
}

__device__ __forceinline__ void write_tile(f2* __restrict__ dst,
                                           const float2* px, const float2* py,
                                           int tid) {
    #pragma unroll
    for (int k = 0; k < NPF; ++k) {
        const int j = tid + 256 * k;                  // chunk id
        const float4 v = make_float4(px[k].x, py[k].x, px[k].y, py[k].y);
        *reinterpret_cast<float4*>(&dst[2 * j]) = v;  // ds_write_b128
    }
}

// Full 6-row x 6-pair window batched into registers; rolling colsum in regs.
__device__ __forceinline__ void compute_channel(const f2* __restrict__ tile,
                                                int ry, int cx,
                                                float* ch0, float* ch1) {
    const float EPS = 1e-4f;
    const f2 EPS2 = {1e-4f, 1e-4f};

    // ---- one burst: 18 independent ds_read_b128 ----
    f2 w[6][6];
    #pragma unroll
    for (int k = 0; k < 6; ++k) {
        const int base = (2 * ry + k) * LW + cx;
        const float4 u0 = *reinterpret_cast<const float4*>(&tile[base]);
        const float4 u1 = *reinterpret_cast<const float4*>(&tile[base + 2]);
        const float4 u2 = *reinterpret_cast<const float4*>(&tile[base + 4]);
        w[k][0] = f2{u0.x, u0.y}; w[k][1] = f2{u0.z, u0.w};
        w[k][2] = f2{u1.x, u1.y}; w[k][3] = f2{u1.z, u1.w};
        w[k][4] = f2{u2.x, u2.y}; w[k][5] = f2{u2.z, u2.w};
    }

    // ---- init column sums from rows 0..3 ----
    f2 cs[6];
    #pragma unroll
    for (int j = 0; j < 6; ++j)
        cs[j] = (w[0][j] + w[1][j]) + (w[2][j] + w[3][j]);

    #pragma unroll
    for (int o = 0; o < 2; ++o) {
        #pragma unroll
        for (int j = 0; j < 6; ++j) cs[j] += w[o + 4][j];

        // means for px0 (cols 0..4) and px1 (cols 1..5), both images packed
        const f2 m4 = (cs[1] + cs[2]) + (cs[3] + cs[4]);
        const f2 M0 = (m4 + cs[0]) * (1.f / 25.f);   // (mx0, my0)
        const f2 M1 = (m4 + cs[5]) * (1.f / 25.f);   // (mx1, my1)

        float a0 = 0.f, a1 = 0.f;
        #pragma unroll
        for (int k = 0; k < 5; ++k) {
            #pragma unroll
            for (int j = 0; j < 5; ++j) {
                {
                    const f2 d = w[o + k][j] - M0;                      // pk_add
                    const float t = d.x * d.y;
                    const float num = fabsf(t) + EPS;
                    const f2 q = __builtin_elementwise_fma(d, d, EPS2); // pk_fma
                    const float den = q.x * q.y;
                    a0 += num * __builtin_amdgcn_rsqf(den);
                }
                {
                    const f2 d = w[o + k][j + 1] - M1;
                    const float t = d.x * d.y;
                    const float num = fabsf(t) + EPS;
                    const f2 q = __builtin_elementwise_fma(d, d, EPS2);
                    const float den = q.x * q.y;
                    a1 += num * __builtin_amdgcn_rsqf(den);
                }
            }
        }
        ch0[o] += fminf(fmaxf(a0 * (1.f / 25.f), 0.f), 1.f);
        ch1[o] += fminf(fmaxf(a1 * (1.f / 25.f), 0.f), 1.f);

        #pragma unroll
        for (int j = 0; j < 6; ++j) cs[j] -= w[o][j];
    }
}

__global__ __launch_bounds__(256, 4)
void zncc_kernel(const float* __restrict__ x,
                 const float* __restrict__ y,
                 float* __restrict__ out) {
    __shared__ f2 sb[2][LPAD];          // interleaved (x,y) tiles, 24576 B

    const int tid = threadIdx.x;
    const int tx  = tid & 31;           // 32 col-pairs -> 64 cols
    const int ry  = tid >> 5;           // 0..7 -> rows 2*ry, 2*ry+1
    const int cx  = 2 * tx;
    const int w0  = blockIdx.x * TW;
    const int h0  = blockIdx.y * TH;
    const int b   = blockIdx.z;

    // staging address math, once (reused for all 3 channels), chunk-based:
    // chunk j covers tile pairs (2j, 2j+1): row l=j/34, cols m=2(j%34).
    // gc = w0+m-2 is always even -> a chunk never straddles the image edge.
    int   goff[NPF];
    float fm[NPF];
    #pragma unroll
    for (int k = 0; k < NPF; ++k) {
        const int j  = tid + 256 * k;
        const int l  = j / 34;
        const int m  = 2 * (j - l * 34);
        const int gr = h0 + l - HALO;
        const int gc = w0 + m - HALO;
        const bool ok = (j < NCH) && ((unsigned)gr < (unsigned)H) &&
                        ((unsigned)gc < (unsigned)W);
        goff[k] = ok ? gr * W + gc : 0;
        fm[k]   = ok ? 1.f : 0.f;
    }

    const float* xb0 = x + (size_t)(b * C) * PLANE;
    const float* yb0 = y + (size_t)(b * C) * PLANE;

    float ch0[2] = {0.f, 0.f};
    float ch1[2] = {0.f, 0.f};
    float2 px[NPF], py[NPF];

    // stage channel 0 -> buf0
    prefetch_plane(xb0, yb0, goff, fm, px, py);
    write_tile(&sb[0][0], px, py, tid);
    __syncthreads();

    // channel 0: prefetch ch1, compute from buf0, write buf1
    prefetch_plane(xb0 + PLANE, yb0 + PLANE, goff, fm, px, py);
    compute_channel(&sb[0][0], ry, cx, ch0, ch1);
    write_tile(&sb[1][0], px, py, tid);
    __syncthreads();

    // channel 1: prefetch ch2, compute from buf1, write buf0
    prefetch_plane(xb0 + 2 * PLANE, yb0 + 2 * PLANE, goff, fm, px, py);
    compute_channel(&sb[1][0], ry, cx, ch0, ch1);
    write_tile(&sb[0][0], px, py, tid);
    __syncthreads();

    // channel 2: compute from buf0
    compute_channel(&sb[0][0], ry, cx, ch0, ch1);

    // write 2x2 output strip
    #pragma unroll
    for (int o = 0; o < 2; ++o) {
        float2 v;
        v.x = ch0[o] * (1.f / 3.f);
        v.y = ch1[o] * (1.f / 3.f);
        *reinterpret_cast<float2*>(
            &out[((size_t)b * H + h0 + 2 * ry + o) * W + w0 + cx]) = v;
    }
}

extern "C" void kernel_launch(void* const* d_in, const int* in_sizes, int n_in,
                              void* d_out, int out_size, void* d_ws, size_t ws_size,
                              hipStream_t stream) {
    const float* x = (const float*)d_in[0];
    const float* y = (const float*)d_in[1];
    float* out = (float*)d_out;
    dim3 grid(W / TW, H / TH, NB);   // 8, 32, 4 = 1024 blocks (4 per CU)
    zncc_kernel<<<grid, dim3(256), 0, stream>>>(x, y, out);
}